// Round 4
// baseline (3477.863 us; speedup 1.0000x reference)
//
#include <hip/hip_runtime.h>
#include <hip/hip_bf16.h>

using bf16 = __hip_bfloat16;

#define D_DIM 512
#define C_DIM 2048
#define U_DIM 4
#define DK 64
#define TQ 4

// Flag-selected load: f=1 -> fp32 data, f=0 -> bf16 data.
__device__ __forceinline__ float dload(const void* p, size_t i, int f) {
    return f ? ((const float*)p)[i] : __bfloat162float(((const bf16*)p)[i]);
}

// ---------------------------------------------------------------------------
// Input dtype detection (robustness; expected flag=1 -> fp32).
// ---------------------------------------------------------------------------
__global__ void detect_kernel(const void* __restrict__ x, int* __restrict__ flag) {
    const bf16* xb = (const bf16*)x;
    int tid = threadIdx.x;
    int cnt = 0;
    for (int i = tid; i < 8192; i += 256) {
        float a = fabsf(__bfloat162float(xb[i]));
        if (!(a <= 100.0f)) cnt++;
    }
    #pragma unroll
    for (int o = 32; o > 0; o >>= 1) cnt += __shfl_down(cnt, o);
    __shared__ int sred[4];
    if ((tid & 63) == 0) sred[tid >> 6] = cnt;
    __syncthreads();
    if (tid == 0) {
        int c = sred[0] + sred[1] + sred[2] + sred[3];
        *flag = (c > 400) ? 1 : 0;
    }
}

// ---------------------------------------------------------------------------
// Per-row mean / rstd for LayerNorm fusion. One block (256 thr) per row, D=512.
// ---------------------------------------------------------------------------
__global__ void row_stats_kernel(const void* __restrict__ x, int x_raw,
                                 float* __restrict__ stats, const int* __restrict__ flagp) {
    int f = x_raw ? *flagp : 1;
    int row = blockIdx.x;
    int tid = threadIdx.x;
    size_t base = (size_t)row * D_DIM;
    float v0 = dload(x, base + tid, f);
    float v1 = dload(x, base + tid + 256, f);
    float s  = v0 + v1;
    float ss = v0 * v0 + v1 * v1;
    #pragma unroll
    for (int o = 32; o > 0; o >>= 1) {
        s  += __shfl_down(s, o);
        ss += __shfl_down(ss, o);
    }
    __shared__ float sred[8];
    int wv = tid >> 6, ln = tid & 63;
    if (ln == 0) { sred[wv] = s; sred[wv + 4] = ss; }
    __syncthreads();
    if (tid == 0) {
        float S  = sred[0] + sred[1] + sred[2] + sred[3];
        float SS = sred[4] + sred[5] + sred[6] + sred[7];
        float mu  = S * (1.0f / D_DIM);
        float var = SS * (1.0f / D_DIM) - mu * mu;
        stats[row * 2]     = mu;
        stats[row * 2 + 1] = rsqrtf(var + 1e-5f);
    }
}

// ---------------------------------------------------------------------------
// Y[N x 512] = (LN? LN(X) : X) @ W + bias.  64x64 tile, 256 thr, 4x4/thread.
// Output is ALWAYS fp32 (d_out is float* per the fp32 reference).
// ---------------------------------------------------------------------------
template <bool LN>
__global__ void gemm_ln_kernel(const void* __restrict__ X, int x_raw,
                               const float* __restrict__ stats,
                               const void* __restrict__ lnw, const void* __restrict__ lnb,
                               const void* __restrict__ W, const void* __restrict__ bias,
                               float* __restrict__ Y, const int* __restrict__ flagp) {
    __shared__ float As[16][68];
    __shared__ float Bs[16][68];
    int f = *flagp;
    int xf = x_raw ? f : 1;
    int tid = threadIdx.x;
    int tx = tid & 15, ty = tid >> 4;
    int row0 = blockIdx.y * 64, col0 = blockIdx.x * 64;
    float acc[4][4] = {};
    for (int kt = 0; kt < D_DIM; kt += 16) {
        #pragma unroll
        for (int i = 0; i < 4; ++i) {
            int e = tid + i * 256;
            int r = e >> 4, kk = e & 15;
            float xv = dload(X, (size_t)(row0 + r) * D_DIM + kt + kk, xf);
            if constexpr (LN) {
                float mu = stats[(row0 + r) * 2];
                float rs = stats[(row0 + r) * 2 + 1];
                xv = (xv - mu) * rs * dload(lnw, kt + kk, f) + dload(lnb, kt + kk, f);
            }
            As[kk][r] = xv;
            int kk2 = e >> 6, c2 = e & 63;
            Bs[kk2][c2] = dload(W, (size_t)(kt + kk2) * D_DIM + col0 + c2, f);
        }
        __syncthreads();
        #pragma unroll
        for (int kk = 0; kk < 16; ++kk) {
            float4 a = *(const float4*)&As[kk][ty * 4];
            float4 b = *(const float4*)&Bs[kk][tx * 4];
            acc[0][0] += a.x * b.x; acc[0][1] += a.x * b.y; acc[0][2] += a.x * b.z; acc[0][3] += a.x * b.w;
            acc[1][0] += a.y * b.x; acc[1][1] += a.y * b.y; acc[1][2] += a.y * b.z; acc[1][3] += a.y * b.w;
            acc[2][0] += a.z * b.x; acc[2][1] += a.z * b.y; acc[2][2] += a.z * b.z; acc[2][3] += a.z * b.w;
            acc[3][0] += a.w * b.x; acc[3][1] += a.w * b.y; acc[3][2] += a.w * b.z; acc[3][3] += a.w * b.w;
        }
        __syncthreads();
    }
    #pragma unroll
    for (int i = 0; i < 4; ++i) {
        int r = row0 + ty * 4 + i;
        #pragma unroll
        for (int j = 0; j < 4; ++j) {
            int c = col0 + tx * 4 + j;
            Y[(size_t)r * D_DIM + c] = acc[i][j] + dload(bias, c, f);
        }
    }
}

// ---------------------------------------------------------------------------
// Fused ColBERT attention. Block = (TQ=4 query tokens) x (1 head), 256 thr.
// ---------------------------------------------------------------------------
__global__ void attn_kernel(const float* __restrict__ qp, const float* __restrict__ kp,
                            const float* __restrict__ vp, float* __restrict__ att) {
    __shared__ float sq[TQ][DK];
    __shared__ float sc[TQ][C_DIM];
    __shared__ float sred[8];
    __shared__ float sinv[TQ];
    __shared__ float part[4][TQ][DK];

    int tid = threadIdx.x;
    int h = blockIdx.y;
    int bt0 = blockIdx.x * TQ;

    {
        int tq = tid >> 6, d = tid & 63;
        sq[tq][d] = qp[(size_t)(bt0 + tq) * D_DIM + h * DK + d];
    }
    __syncthreads();

    int u = tid & 3;
    int csub = tid >> 2;
    for (int it = 0; it < 32; ++it) {
        int c = it * 64 + csub;
        const float* kv = kp + (size_t)(c * U_DIM + u) * D_DIM + h * DK;
        float4 kr[16];
        #pragma unroll
        for (int dd = 0; dd < 16; ++dd) kr[dd] = ((const float4*)kv)[dd];
        #pragma unroll
        for (int tq = 0; tq < TQ; ++tq) {
            float s = 0.0f;
            #pragma unroll
            for (int dd = 0; dd < 16; ++dd) {
                float4 qv = *(const float4*)&sq[tq][dd * 4];
                s += qv.x * kr[dd].x + qv.y * kr[dd].y + qv.z * kr[dd].z + qv.w * kr[dd].w;
            }
            s = fmaxf(s, __shfl_xor(s, 1));
            s = fmaxf(s, __shfl_xor(s, 2));
            if (u == 0) sc[tq][c] = s * 0.125f;
        }
    }
    __syncthreads();

    for (int tq = 0; tq < TQ; ++tq) {
        float m = -1e30f;
        for (int j = tid; j < C_DIM; j += 256) m = fmaxf(m, sc[tq][j]);
        #pragma unroll
        for (int o = 32; o > 0; o >>= 1) m = fmaxf(m, __shfl_down(m, o));
        if ((tid & 63) == 0) sred[tid >> 6] = m;
        __syncthreads();
        m = fmaxf(fmaxf(sred[0], sred[1]), fmaxf(sred[2], sred[3]));
        __syncthreads();
        float s = 0.0f;
        for (int j = tid; j < C_DIM; j += 256) {
            float e = __expf(sc[tq][j] - m);
            sc[tq][j] = e;
            s += e;
        }
        #pragma unroll
        for (int o = 32; o > 0; o >>= 1) s += __shfl_down(s, o);
        if ((tid & 63) == 0) sred[tid >> 6] = s;
        __syncthreads();
        if (tid == 0) sinv[tq] = 1.0f / (sred[0] + sred[1] + sred[2] + sred[3]);
        __syncthreads();
    }

    int d = tid & 63, g = tid >> 6;
    float acc[TQ] = {};
    for (int c = g; c < C_DIM; c += 4) {
        float vd = vp[(size_t)c * D_DIM + h * DK + d];
        #pragma unroll
        for (int tq = 0; tq < TQ; ++tq) acc[tq] += sc[tq][c] * vd;
    }
    #pragma unroll
    for (int tq = 0; tq < TQ; ++tq) part[g][tq][d] = acc[tq];
    __syncthreads();
    {
        int tq = tid >> 6, dd = tid & 63;
        float o = (part[0][tq][dd] + part[1][tq][dd] + part[2][tq][dd] + part[3][tq][dd]) * sinv[tq];
        att[(size_t)(bt0 + tq) * D_DIM + h * DK + dd] = o;
    }
}

extern "C" void kernel_launch(void* const* d_in, const int* in_sizes, int n_in,
                              void* d_out, int out_size, void* d_ws, size_t ws_size,
                              hipStream_t stream) {
    const void* model_embed = d_in[0];
    const void* ctx_key     = d_in[1];
    const void* ctx_val     = d_in[2];
    const void* ln1w = d_in[3];  const void* ln1b = d_in[4];
    const void* ln2w = d_in[5];  const void* ln2b = d_in[6];
    const void* ln3w = d_in[7];  const void* ln3b = d_in[8];
    const void* ln4w = d_in[9];  const void* ln4b = d_in[10];
    const void* wq = d_in[11];   const void* bq = d_in[12];
    const void* wk = d_in[13];   const void* bk = d_in[14];
    const void* wv = d_in[15];   const void* bv = d_in[16];
    const void* wo = d_in[17];   const void* bo = d_in[18];
    const void* wp = d_in[19];   const void* bp = d_in[20];

    int*   flagp  = (int*)d_ws;
    float* ws     = (float*)d_ws + 16;
    float* qp     = ws;                    // 1024*512
    float* kp     = qp + 1024 * 512;       // 8192*512
    float* vp     = kp + 8192 * 512;       // 2048*512
    float* att    = vp + 2048 * 512;       // 1024*512
    float* o1     = att + 1024 * 512;      // 1024*512
    float* statsQ = o1 + 1024 * 512;       // 2048
    float* statsK = statsQ + 2048;         // 16384
    float* statsV = statsK + 16384;        // 4096
    float* statsO = statsV + 4096;         // 2048

    detect_kernel<<<1, 256, 0, stream>>>(model_embed, flagp);

    row_stats_kernel<<<1024, 256, 0, stream>>>(model_embed, 1, statsQ, flagp);
    row_stats_kernel<<<8192, 256, 0, stream>>>(ctx_key, 1, statsK, flagp);
    row_stats_kernel<<<2048, 256, 0, stream>>>(ctx_val, 1, statsV, flagp);

    gemm_ln_kernel<true><<<dim3(8, 16), 256, 0, stream>>>(model_embed, 1, statsQ, ln1w, ln1b, wq, bq, qp, flagp);
    gemm_ln_kernel<true><<<dim3(8, 128), 256, 0, stream>>>(ctx_key, 1, statsK, ln2w, ln2b, wk, bk, kp, flagp);
    gemm_ln_kernel<true><<<dim3(8, 32), 256, 0, stream>>>(ctx_val, 1, statsV, ln3w, ln3b, wv, bv, vp, flagp);

    attn_kernel<<<dim3(256, 8), 256, 0, stream>>>(qp, kp, vp, att);

    gemm_ln_kernel<false><<<dim3(8, 16), 256, 0, stream>>>(att, 0, nullptr, nullptr, nullptr, wo, bo, o1, flagp);
    row_stats_kernel<<<1024, 256, 0, stream>>>(o1, 0, statsO, flagp);
    gemm_ln_kernel<true><<<dim3(8, 16), 256, 0, stream>>>(o1, 0, statsO, ln4w, ln4b, wp, bp, (float*)d_out, flagp);
}

// Round 5
// 3229.078 us; speedup vs baseline: 1.0770x; 1.0770x over previous
//
#include <hip/hip_runtime.h>
#include <hip/hip_bf16.h>

using bf16 = __hip_bfloat16;

#define D_DIM 512
#define C_DIM 2048
#define U_DIM 4
#define DK 64
#define TQ 4

// Flag-selected load: f=1 -> fp32 data, f=0 -> bf16 data.
__device__ __forceinline__ float dload(const void* p, size_t i, int f) {
    return f ? ((const float*)p)[i] : __bfloat162float(((const bf16*)p)[i]);
}

// ---------------------------------------------------------------------------
// Input dtype detection (robustness; expected flag=1 -> fp32).
// ---------------------------------------------------------------------------
__global__ void detect_kernel(const void* __restrict__ x, int* __restrict__ flag) {
    const bf16* xb = (const bf16*)x;
    int tid = threadIdx.x;
    int cnt = 0;
    for (int i = tid; i < 8192; i += 256) {
        float a = fabsf(__bfloat162float(xb[i]));
        if (!(a <= 100.0f)) cnt++;
    }
    #pragma unroll
    for (int o = 32; o > 0; o >>= 1) cnt += __shfl_down(cnt, o);
    __shared__ int sred[4];
    if ((tid & 63) == 0) sred[tid >> 6] = cnt;
    __syncthreads();
    if (tid == 0) {
        int c = sred[0] + sred[1] + sred[2] + sred[3];
        *flag = (c > 400) ? 1 : 0;
    }
}

// ---------------------------------------------------------------------------
// Per-row mean / rstd for LayerNorm fusion. One block (256 thr) per row, D=512.
// ---------------------------------------------------------------------------
__global__ void row_stats_kernel(const void* __restrict__ x, int x_raw,
                                 float* __restrict__ stats, const int* __restrict__ flagp) {
    int f = x_raw ? *flagp : 1;
    int row = blockIdx.x;
    int tid = threadIdx.x;
    size_t base = (size_t)row * D_DIM;
    float v0 = dload(x, base + tid, f);
    float v1 = dload(x, base + tid + 256, f);
    float s  = v0 + v1;
    float ss = v0 * v0 + v1 * v1;
    #pragma unroll
    for (int o = 32; o > 0; o >>= 1) {
        s  += __shfl_down(s, o);
        ss += __shfl_down(ss, o);
    }
    __shared__ float sred[8];
    int wv = tid >> 6, ln = tid & 63;
    if (ln == 0) { sred[wv] = s; sred[wv + 4] = ss; }
    __syncthreads();
    if (tid == 0) {
        float S  = sred[0] + sred[1] + sred[2] + sred[3];
        float SS = sred[4] + sred[5] + sred[6] + sred[7];
        float mu  = S * (1.0f / D_DIM);
        float var = SS * (1.0f / D_DIM) - mu * mu;
        stats[row * 2]     = mu;
        stats[row * 2 + 1] = rsqrtf(var + 1e-5f);
    }
}

// ---------------------------------------------------------------------------
// Y[N x 512] = (LN? LN(X) : X) @ W + bias.  64x64 tile, 256 thr, 4x4/thread.
// ---------------------------------------------------------------------------
template <bool LN>
__global__ void gemm_ln_kernel(const void* __restrict__ X, int x_raw,
                               const float* __restrict__ stats,
                               const void* __restrict__ lnw, const void* __restrict__ lnb,
                               const void* __restrict__ W, const void* __restrict__ bias,
                               float* __restrict__ Y, const int* __restrict__ flagp) {
    __shared__ float As[16][68];
    __shared__ float Bs[16][68];
    int f = *flagp;
    int xf = x_raw ? f : 1;
    int tid = threadIdx.x;
    int tx = tid & 15, ty = tid >> 4;
    int row0 = blockIdx.y * 64, col0 = blockIdx.x * 64;
    float acc[4][4] = {};
    for (int kt = 0; kt < D_DIM; kt += 16) {
        #pragma unroll
        for (int i = 0; i < 4; ++i) {
            int e = tid + i * 256;
            int r = e >> 4, kk = e & 15;
            float xv = dload(X, (size_t)(row0 + r) * D_DIM + kt + kk, xf);
            if constexpr (LN) {
                float mu = stats[(row0 + r) * 2];
                float rs = stats[(row0 + r) * 2 + 1];
                xv = (xv - mu) * rs * dload(lnw, kt + kk, f) + dload(lnb, kt + kk, f);
            }
            As[kk][r] = xv;
            int kk2 = e >> 6, c2 = e & 63;
            Bs[kk2][c2] = dload(W, (size_t)(kt + kk2) * D_DIM + col0 + c2, f);
        }
        __syncthreads();
        #pragma unroll
        for (int kk = 0; kk < 16; ++kk) {
            float4 a = *(const float4*)&As[kk][ty * 4];
            float4 b = *(const float4*)&Bs[kk][tx * 4];
            acc[0][0] += a.x * b.x; acc[0][1] += a.x * b.y; acc[0][2] += a.x * b.z; acc[0][3] += a.x * b.w;
            acc[1][0] += a.y * b.x; acc[1][1] += a.y * b.y; acc[1][2] += a.y * b.z; acc[1][3] += a.y * b.w;
            acc[2][0] += a.z * b.x; acc[2][1] += a.z * b.y; acc[2][2] += a.z * b.z; acc[2][3] += a.z * b.w;
            acc[3][0] += a.w * b.x; acc[3][1] += a.w * b.y; acc[3][2] += a.w * b.z; acc[3][3] += a.w * b.w;
        }
        __syncthreads();
    }
    #pragma unroll
    for (int i = 0; i < 4; ++i) {
        int r = row0 + ty * 4 + i;
        #pragma unroll
        for (int j = 0; j < 4; ++j) {
            int c = col0 + tx * 4 + j;
            Y[(size_t)r * D_DIM + c] = acc[i][j] + dload(bias, c, f);
        }
    }
}

// ---------------------------------------------------------------------------
// Fused ColBERT attention. 1-D grid of 2048 blocks, XCD-swizzled:
// h = blockIdx.x % 8 so all blocks resident on one XCD share a head ->
// that head's K-slice (2 MB) + V-slice (0.5 MB) fits the 4 MB per-XCD L2.
// Block = TQ=4 query tokens x 1 head, 256 thr.
// ---------------------------------------------------------------------------
__global__ void attn_kernel(const float* __restrict__ qp, const float* __restrict__ kp,
                            const float* __restrict__ vp, float* __restrict__ att) {
    __shared__ float sq[TQ][DK];
    __shared__ float sc[TQ][C_DIM];
    __shared__ float sred[8];
    __shared__ float sinv[TQ];
    __shared__ float part[4][TQ][DK];

    int tid = threadIdx.x;
    int h = blockIdx.x & 7;            // XCD-aware: same-XCD blocks share h
    int bt0 = (blockIdx.x >> 3) * TQ;

    {
        int tq = tid >> 6, d = tid & 63;
        sq[tq][d] = qp[(size_t)(bt0 + tq) * D_DIM + h * DK + d];
    }
    __syncthreads();

    int u = tid & 3;
    int csub = tid >> 2;
    for (int it = 0; it < 32; ++it) {
        int c = it * 64 + csub;
        const float* kv = kp + (size_t)(c * U_DIM + u) * D_DIM + h * DK;
        float4 kr[16];
        #pragma unroll
        for (int dd = 0; dd < 16; ++dd) kr[dd] = ((const float4*)kv)[dd];
        #pragma unroll
        for (int tq = 0; tq < TQ; ++tq) {
            float s = 0.0f;
            #pragma unroll
            for (int dd = 0; dd < 16; ++dd) {
                float4 qv = *(const float4*)&sq[tq][dd * 4];
                s += qv.x * kr[dd].x + qv.y * kr[dd].y + qv.z * kr[dd].z + qv.w * kr[dd].w;
            }
            s = fmaxf(s, __shfl_xor(s, 1));
            s = fmaxf(s, __shfl_xor(s, 2));
            if (u == 0) sc[tq][c] = s * 0.125f;
        }
    }
    __syncthreads();

    for (int tq = 0; tq < TQ; ++tq) {
        float m = -1e30f;
        for (int j = tid; j < C_DIM; j += 256) m = fmaxf(m, sc[tq][j]);
        #pragma unroll
        for (int o = 32; o > 0; o >>= 1) m = fmaxf(m, __shfl_down(m, o));
        if ((tid & 63) == 0) sred[tid >> 6] = m;
        __syncthreads();
        m = fmaxf(fmaxf(sred[0], sred[1]), fmaxf(sred[2], sred[3]));
        __syncthreads();
        float s = 0.0f;
        for (int j = tid; j < C_DIM; j += 256) {
            float e = __expf(sc[tq][j] - m);
            sc[tq][j] = e;
            s += e;
        }
        #pragma unroll
        for (int o = 32; o > 0; o >>= 1) s += __shfl_down(s, o);
        if ((tid & 63) == 0) sred[tid >> 6] = s;
        __syncthreads();
        if (tid == 0) sinv[tq] = 1.0f / (sred[0] + sred[1] + sred[2] + sred[3]);
        __syncthreads();
    }

    int d = tid & 63, g = tid >> 6;
    float acc[TQ] = {};
    for (int c = g; c < C_DIM; c += 4) {
        float vd = vp[(size_t)c * D_DIM + h * DK + d];
        #pragma unroll
        for (int tq = 0; tq < TQ; ++tq) acc[tq] += sc[tq][c] * vd;
    }
    #pragma unroll
    for (int tq = 0; tq < TQ; ++tq) part[g][tq][d] = acc[tq];
    __syncthreads();
    {
        int tq = tid >> 6, dd = tid & 63;
        float o = (part[0][tq][dd] + part[1][tq][dd] + part[2][tq][dd] + part[3][tq][dd]) * sinv[tq];
        att[(size_t)(bt0 + tq) * D_DIM + h * DK + dd] = o;
    }
}

extern "C" void kernel_launch(void* const* d_in, const int* in_sizes, int n_in,
                              void* d_out, int out_size, void* d_ws, size_t ws_size,
                              hipStream_t stream) {
    const void* model_embed = d_in[0];
    const void* ctx_key     = d_in[1];
    const void* ctx_val     = d_in[2];
    const void* ln1w = d_in[3];  const void* ln1b = d_in[4];
    const void* ln2w = d_in[5];  const void* ln2b = d_in[6];
    const void* ln3w = d_in[7];  const void* ln3b = d_in[8];
    const void* ln4w = d_in[9];  const void* ln4b = d_in[10];
    const void* wq = d_in[11];   const void* bq = d_in[12];
    const void* wk = d_in[13];   const void* bk = d_in[14];
    const void* wv = d_in[15];   const void* bv = d_in[16];
    const void* wo = d_in[17];   const void* bo = d_in[18];
    const void* wp = d_in[19];   const void* bp = d_in[20];

    int*   flagp  = (int*)d_ws;
    float* ws     = (float*)d_ws + 16;
    float* qp     = ws;                    // 1024*512
    float* kp     = qp + 1024 * 512;       // 8192*512
    float* vp     = kp + 8192 * 512;       // 2048*512
    float* att    = vp + 2048 * 512;       // 1024*512
    float* o1     = att + 1024 * 512;      // 1024*512
    float* statsQ = o1 + 1024 * 512;       // 2048
    float* statsK = statsQ + 2048;         // 16384
    float* statsV = statsK + 16384;        // 4096
    float* statsO = statsV + 4096;         // 2048

    detect_kernel<<<1, 256, 0, stream>>>(model_embed, flagp);

    row_stats_kernel<<<1024, 256, 0, stream>>>(model_embed, 1, statsQ, flagp);
    row_stats_kernel<<<8192, 256, 0, stream>>>(ctx_key, 1, statsK, flagp);
    row_stats_kernel<<<2048, 256, 0, stream>>>(ctx_val, 1, statsV, flagp);

    gemm_ln_kernel<true><<<dim3(8, 16), 256, 0, stream>>>(model_embed, 1, statsQ, ln1w, ln1b, wq, bq, qp, flagp);
    gemm_ln_kernel<true><<<dim3(8, 128), 256, 0, stream>>>(ctx_key, 1, statsK, ln2w, ln2b, wk, bk, kp, flagp);
    gemm_ln_kernel<true><<<dim3(8, 32), 256, 0, stream>>>(ctx_val, 1, statsV, ln3w, ln3b, wv, bv, vp, flagp);

    attn_kernel<<<2048, 256, 0, stream>>>(qp, kp, vp, att);

    gemm_ln_kernel<false><<<dim3(8, 16), 256, 0, stream>>>(att, 0, nullptr, nullptr, nullptr, wo, bo, o1, flagp);
    row_stats_kernel<<<1024, 256, 0, stream>>>(o1, 0, statsO, flagp);
    gemm_ln_kernel<true><<<dim3(8, 16), 256, 0, stream>>>(o1, 0, statsO, ln4w, ln4b, wp, bp, (float*)d_out, flagp);
}